// Round 1
// baseline (4356.571 us; speedup 1.0000x reference)
//
#include <hip/hip_runtime.h>

#define NN 100000
#define NE 1000000
#define NG 1000
#define H 128
#define NLAYER 4
#define NEG 0.2f

__device__ __forceinline__ float lrelu(float x) { return x >= 0.f ? x : NEG * x; }

// ---------------- Atom encoder: h[n][c] = sum_f emb[f][nfeats[n][f]][c] ----------------
__global__ __launch_bounds__(256) void k_atom(const int* __restrict__ nfeats,
                                              const float* __restrict__ emb,
                                              float* __restrict__ h) {
    int node = blockIdx.x * 2 + (threadIdx.x >> 7);
    int c = threadIdx.x & 127;
    if (node >= NN) return;
    float acc = 0.f;
#pragma unroll
    for (int f = 0; f < 9; ++f) {
        int idx = nfeats[node * 9 + f];
        acc += emb[((f << 6) + idx) * H + c];  // V = 64
    }
    h[node * H + c] = acc;
}

// ---------------- Fused q/k GEMM: q = h@Wq + bq, k = h@Wk + bk (32-row tile) ----------------
__global__ __launch_bounds__(256) void k_gemm_qk(const float* __restrict__ h,
                                                 const float* __restrict__ Wq,
                                                 const float* __restrict__ bq,
                                                 const float* __restrict__ Wk,
                                                 const float* __restrict__ bk,
                                                 float* __restrict__ q,
                                                 float* __restrict__ k) {
    __shared__ float hs[32 * H];
    int row0 = blockIdx.x * 32;
    int tid = threadIdx.x;

    const float4* src4 = (const float4*)(h + (size_t)row0 * H);
    float4* dst4 = (float4*)hs;
#pragma unroll
    for (int i = 0; i < 4; ++i) dst4[tid + i * 256] = src4[tid + i * 256];
    __syncthreads();

    int c = tid & 127;
    int rh = tid >> 7;  // 0..1, 16 rows each
    float accq[16], acck[16];
    float bqv = bq[c], bkv = bk[c];
#pragma unroll
    for (int r = 0; r < 16; ++r) { accq[r] = bqv; acck[r] = bkv; }

    const float* hsb = hs + rh * 16 * H;
    for (int j4 = 0; j4 < 32; ++j4) {
        int j = j4 * 4;
        float wq0 = Wq[(j + 0) * H + c];
        float wq1 = Wq[(j + 1) * H + c];
        float wq2 = Wq[(j + 2) * H + c];
        float wq3 = Wq[(j + 3) * H + c];
        float wk0 = Wk[(j + 0) * H + c];
        float wk1 = Wk[(j + 1) * H + c];
        float wk2 = Wk[(j + 2) * H + c];
        float wk3 = Wk[(j + 3) * H + c];
#pragma unroll
        for (int r = 0; r < 16; ++r) {
            float4 hv = *(const float4*)(hsb + r * H + j);
            accq[r] += hv.x * wq0 + hv.y * wq1 + hv.z * wq2 + hv.w * wq3;
            acck[r] += hv.x * wk0 + hv.y * wk1 + hv.z * wk2 + hv.w * wk3;
        }
    }
#pragma unroll
    for (int r = 0; r < 16; ++r) {
        int row = row0 + rh * 16 + r;
        q[(size_t)row * H + c] = accq[r];
        k[(size_t)row * H + c] = acck[r];
    }
}

// ---------------- h_new = lrelu(agg@Wr + br) ----------------
__global__ __launch_bounds__(256) void k_gemm_r(const float* __restrict__ agg,
                                                const float* __restrict__ Wr,
                                                const float* __restrict__ br,
                                                float* __restrict__ hout) {
    __shared__ float hs[32 * H];
    int row0 = blockIdx.x * 32;
    int tid = threadIdx.x;

    const float4* src4 = (const float4*)(agg + (size_t)row0 * H);
    float4* dst4 = (float4*)hs;
#pragma unroll
    for (int i = 0; i < 4; ++i) dst4[tid + i * 256] = src4[tid + i * 256];
    __syncthreads();

    int c = tid & 127;
    int rh = tid >> 7;
    float acc[16];
    float bv = br[c];
#pragma unroll
    for (int r = 0; r < 16; ++r) acc[r] = bv;

    const float* hsb = hs + rh * 16 * H;
    for (int j4 = 0; j4 < 32; ++j4) {
        int j = j4 * 4;
        float w0 = Wr[(j + 0) * H + c];
        float w1 = Wr[(j + 1) * H + c];
        float w2 = Wr[(j + 2) * H + c];
        float w3 = Wr[(j + 3) * H + c];
#pragma unroll
        for (int r = 0; r < 16; ++r) {
            float4 hv = *(const float4*)(hsb + r * H + j);
            acc[r] += hv.x * w0 + hv.y * w1 + hv.z * w2 + hv.w * w3;
        }
    }
#pragma unroll
    for (int r = 0; r < 16; ++r) {
        int row = row0 + rh * 16 + r;
        hout[(size_t)row * H + c] = lrelu(acc[r]);
    }
}

// ---------------- edge message + scatter: agg[dst] += lrelu(q[dst]+k[src]) ----------------
__global__ __launch_bounds__(256) void k_edge(const float* __restrict__ q,
                                              const float* __restrict__ k,
                                              const int* __restrict__ src,
                                              const int* __restrict__ dst,
                                              float* __restrict__ agg) {
    int gtid = blockIdx.x * blockDim.x + threadIdx.x;
    int wid = gtid >> 6;
    int lane = threadIdx.x & 63;
    int nw = (gridDim.x * blockDim.x) >> 6;
    for (int e = wid; e < NE; e += nw) {
        int s = src[e];
        int d = dst[e];
        float2 qv = *(const float2*)(q + (size_t)d * H + lane * 2);
        float2 kv = *(const float2*)(k + (size_t)s * H + lane * 2);
        float mx = lrelu(qv.x + kv.x);
        float my = lrelu(qv.y + kv.y);
        float* ap = agg + (size_t)d * H + lane * 2;
        atomicAdd(ap, mx);
        atomicAdd(ap + 1, my);
    }
}

// ---------------- graph sum pooling: hg[gid[n]] += h[n] ----------------
__global__ __launch_bounds__(256) void k_pool(const float* __restrict__ h,
                                              const int* __restrict__ gid,
                                              float* __restrict__ hg) {
    int gtid = blockIdx.x * blockDim.x + threadIdx.x;
    int wid = gtid >> 6;
    int lane = threadIdx.x & 63;
    int nw = (gridDim.x * blockDim.x) >> 6;
    for (int n = wid; n < NN; n += nw) {
        int g = gid[n];
        float2 hv = *(const float2*)(h + (size_t)n * H + lane * 2);
        float* ap = hg + (size_t)g * H + lane * 2;
        atomicAdd(ap, hv.x);
        atomicAdd(ap + 1, hv.y);
    }
}

// ---------------- MLP layer 1: x1 = hg@W1 + b1  [G,128]@[128,64] ----------------
__global__ void k_mlp1(const float* __restrict__ hg, const float* __restrict__ W1,
                       const float* __restrict__ b1, float* __restrict__ x1) {
    __shared__ float row[128];
    int g = blockIdx.x;
    int c = threadIdx.x;  // 64
    row[c] = hg[g * H + c];
    row[c + 64] = hg[g * H + c + 64];
    __syncthreads();
    float acc = b1[c];
    for (int j = 0; j < 128; ++j) acc += row[j] * W1[j * 64 + c];
    x1[g * 64 + c] = acc;
}

// ---------------- batchnorm stats over G rows ----------------
template <int C>
__global__ void k_bnstats(const float* __restrict__ x, float* __restrict__ stats) {
    int c = threadIdx.x;
    float sum = 0.f;
    for (int g = 0; g < NG; ++g) sum += x[g * C + c];
    float mu = sum / NG;
    float s2 = 0.f;
    for (int g = 0; g < NG; ++g) {
        float dv = x[g * C + c] - mu;
        s2 += dv * dv;
    }
    stats[c] = mu;
    stats[C + c] = rsqrtf(s2 / NG + 1e-5f);
}

// ---------------- batchnorm apply + lrelu (in place) ----------------
template <int C>
__global__ void k_bnapply(float* __restrict__ x, const float* __restrict__ stats,
                          const float* __restrict__ gm, const float* __restrict__ bt) {
    int i = blockIdx.x * blockDim.x + threadIdx.x;
    if (i >= NG * C) return;
    int c = i & (C - 1);
    float v = (x[i] - stats[c]) * stats[C + c] * gm[c] + bt[c];
    x[i] = lrelu(v);
}

// ---------------- MLP layer 2: x2 = x1@W2 + b2  [G,64]@[64,32] ----------------
__global__ void k_mlp2(const float* __restrict__ x1, const float* __restrict__ W2,
                       const float* __restrict__ b2, float* __restrict__ x2) {
    __shared__ float row[64];
    int g = blockIdx.x;
    int c = threadIdx.x;  // 32
    row[c] = x1[g * 64 + c];
    row[c + 32] = x1[g * 64 + c + 32];
    __syncthreads();
    float acc = b2[c];
    for (int j = 0; j < 64; ++j) acc += row[j] * W2[j * 32 + c];
    x2[g * 32 + c] = acc;
}

// ---------------- MLP layer 3: out = x2@W3 + b3  [G,32]@[32,1] ----------------
__global__ void k_mlp3(const float* __restrict__ x2, const float* __restrict__ W3,
                       const float* __restrict__ b3, float* __restrict__ out) {
    int g = blockIdx.x * blockDim.x + threadIdx.x;
    if (g >= NG) return;
    float acc = b3[0];
    for (int j = 0; j < 32; ++j) acc += x2[g * 32 + j] * W3[j];
    out[g] = acc;
}

extern "C" void kernel_launch(void* const* d_in, const int* in_sizes, int n_in,
                              void* d_out, int out_size, void* d_ws, size_t ws_size,
                              hipStream_t stream) {
    const int* nfeats = (const int*)d_in[0];
    // d_in[1] = efeats (unused by reference)
    const int* src = (const int*)d_in[2];
    const int* dst = (const int*)d_in[3];
    const int* gid = (const int*)d_in[4];
    const float* emb = (const float*)d_in[5];
    const float* Wq = (const float*)d_in[6];
    const float* bq = (const float*)d_in[7];
    const float* Wk = (const float*)d_in[8];
    const float* bk = (const float*)d_in[9];
    const float* Wr = (const float*)d_in[10];
    const float* br = (const float*)d_in[11];
    const float* W1 = (const float*)d_in[12];
    const float* b1 = (const float*)d_in[13];
    const float* g1 = (const float*)d_in[14];
    const float* be1 = (const float*)d_in[15];
    const float* W2 = (const float*)d_in[16];
    const float* b2 = (const float*)d_in[17];
    const float* g2 = (const float*)d_in[18];
    const float* be2 = (const float*)d_in[19];
    const float* W3 = (const float*)d_in[20];
    const float* b3 = (const float*)d_in[21];
    float* out = (float*)d_out;

    size_t nh = (size_t)NN * H;
    float* P0 = (float*)d_ws;
    float* P1 = P0 + nh;
    float* P2 = P1 + nh;
    float* hg = P2 + nh;
    float* x1 = hg + (size_t)NG * H;
    float* x2 = x1 + (size_t)NG * 64;
    float* st = x2 + (size_t)NG * 32;

    k_atom<<<NN / 2, 256, 0, stream>>>(nfeats, emb, P0);

    float* h = P0;
    float* q = P1;
    float* k = P2;
    for (int l = 0; l < NLAYER; ++l) {
        k_gemm_qk<<<NN / 32, 256, 0, stream>>>(h, Wq + (size_t)l * H * H, bq + l * H,
                                               Wk + (size_t)l * H * H, bk + l * H, q, k);
        hipMemsetAsync(h, 0, nh * sizeof(float), stream);  // h is dead; reuse as agg
        k_edge<<<8192, 256, 0, stream>>>(q, k, src, dst, h);
        k_gemm_r<<<NN / 32, 256, 0, stream>>>(h, Wr + (size_t)l * H * H, br + l * H, q);
        // rotate: new h lives in old q buffer
        float* newh = q;
        q = k;
        k = h;
        h = newh;
    }

    hipMemsetAsync(hg, 0, (size_t)NG * H * sizeof(float), stream);
    k_pool<<<2048, 256, 0, stream>>>(h, gid, hg);

    k_mlp1<<<NG, 64, 0, stream>>>(hg, W1, b1, x1);
    k_bnstats<64><<<1, 64, 0, stream>>>(x1, st);
    k_bnapply<64><<<(NG * 64 + 255) / 256, 256, 0, stream>>>(x1, st, g1, be1);
    k_mlp2<<<NG, 32, 0, stream>>>(x1, W2, b2, x2);
    k_bnstats<32><<<1, 32, 0, stream>>>(x2, st);
    k_bnapply<32><<<(NG * 32 + 255) / 256, 256, 0, stream>>>(x2, st, g2, be2);
    k_mlp3<<<(NG + 255) / 256, 256, 0, stream>>>(x2, W3, b3, out);
}

// Round 2
// 1659.587 us; speedup vs baseline: 2.6251x; 2.6251x over previous
//
#include <hip/hip_runtime.h>

#define NN 100000
#define NE 1000000
#define NG 1000
#define H 128
#define NLAYER 4
#define NEG 0.2f

__device__ __forceinline__ float lrelu(float x) { return x >= 0.f ? x : NEG * x; }

// ---------------- Atom encoder: h[n][c] = sum_f emb[f][nfeats[n][f]][c] ----------------
__global__ __launch_bounds__(256) void k_atom(const int* __restrict__ nfeats,
                                              const float* __restrict__ emb,
                                              float* __restrict__ h) {
    int node = blockIdx.x * 2 + (threadIdx.x >> 7);
    int c = threadIdx.x & 127;
    if (node >= NN) return;
    float acc = 0.f;
#pragma unroll
    for (int f = 0; f < 9; ++f) {
        int idx = nfeats[node * 9 + f];
        acc += emb[((f << 6) + idx) * H + c];  // V = 64
    }
    h[node * H + c] = acc;
}

// ---------------- CSR build: histogram of dst ----------------
__global__ __launch_bounds__(256) void k_hist(const int* __restrict__ dst,
                                              int* __restrict__ deg) {
    int i = blockIdx.x * blockDim.x + threadIdx.x;
    if (i < NE) atomicAdd(&deg[dst[i]], 1);
}

// ---------------- CSR build: exclusive scan over deg -> rowp (single block) ----------------
__global__ __launch_bounds__(1024) void k_scan(const int* __restrict__ deg,
                                               int* __restrict__ rowp) {
    __shared__ int part[1024];
    int t = threadIdx.x;
    const int chunk = (NN + 1023) / 1024;  // 98
    int begin = t * chunk;
    int endi = begin + chunk;
    if (endi > NN) endi = NN;
    int s = 0;
    for (int i = begin; i < endi; ++i) s += deg[i];
    part[t] = s;
    __syncthreads();
    for (int off = 1; off < 1024; off <<= 1) {
        int v = (t >= off) ? part[t - off] : 0;
        __syncthreads();
        part[t] += v;
        __syncthreads();
    }
    int run = (t == 0) ? 0 : part[t - 1];
    for (int i = begin; i < endi; ++i) {
        rowp[i] = run;
        run += deg[i];
    }
    if (t == 1023) rowp[NN] = part[1023];
}

// ---------------- CSR build: scatter src ids into dst-sorted order ----------------
__global__ __launch_bounds__(256) void k_scatter(const int* __restrict__ src,
                                                 const int* __restrict__ dst,
                                                 int* __restrict__ cursor,
                                                 int* __restrict__ csr_src) {
    int i = blockIdx.x * blockDim.x + threadIdx.x;
    if (i < NE) {
        int pos = atomicAdd(&cursor[dst[i]], 1);
        csr_src[pos] = src[i];
    }
}

// ---------------- aggregation (gather): agg[n] = sum_{e in in(n)} lrelu(q[n]+k[src_e]) ----------------
__global__ __launch_bounds__(256) void k_agg(const float* __restrict__ q,
                                             const float* __restrict__ k,
                                             const int* __restrict__ rowp,
                                             const int* __restrict__ csr_src,
                                             float* __restrict__ agg) {
    int node = blockIdx.x * 4 + (threadIdx.x >> 6);
    if (node >= NN) return;
    int lane = threadIdx.x & 63;
    int start = rowp[node];
    int end = rowp[node + 1];
    float2 qv = *(const float2*)(q + (size_t)node * H + lane * 2);
    float accx = 0.f, accy = 0.f;
    for (int base = start; base < end; base += 64) {
        int cnt = end - base;
        if (cnt > 64) cnt = 64;
        int sid = (lane < cnt) ? csr_src[base + lane] : 0;
        for (int j = 0; j < cnt; ++j) {
            int s = __shfl(sid, j);
            float2 kv = *(const float2*)(k + (size_t)s * H + lane * 2);
            accx += lrelu(qv.x + kv.x);
            accy += lrelu(qv.y + kv.y);
        }
    }
    float2 o;
    o.x = accx;
    o.y = accy;
    *(float2*)(agg + (size_t)node * H + lane * 2) = o;
}

// ---------------- Fused q/k GEMM: q = h@Wq + bq, k = h@Wk + bk (32-row tile) ----------------
__global__ __launch_bounds__(256) void k_gemm_qk(const float* __restrict__ h,
                                                 const float* __restrict__ Wq,
                                                 const float* __restrict__ bq,
                                                 const float* __restrict__ Wk,
                                                 const float* __restrict__ bk,
                                                 float* __restrict__ q,
                                                 float* __restrict__ k) {
    __shared__ float hs[32 * H];
    int row0 = blockIdx.x * 32;
    int tid = threadIdx.x;

    const float4* src4 = (const float4*)(h + (size_t)row0 * H);
    float4* dst4 = (float4*)hs;
#pragma unroll
    for (int i = 0; i < 4; ++i) dst4[tid + i * 256] = src4[tid + i * 256];
    __syncthreads();

    int c = tid & 127;
    int rh = tid >> 7;  // 0..1, 16 rows each
    float accq[16], acck[16];
    float bqv = bq[c], bkv = bk[c];
#pragma unroll
    for (int r = 0; r < 16; ++r) { accq[r] = bqv; acck[r] = bkv; }

    const float* hsb = hs + rh * 16 * H;
    for (int j4 = 0; j4 < 32; ++j4) {
        int j = j4 * 4;
        float wq0 = Wq[(j + 0) * H + c];
        float wq1 = Wq[(j + 1) * H + c];
        float wq2 = Wq[(j + 2) * H + c];
        float wq3 = Wq[(j + 3) * H + c];
        float wk0 = Wk[(j + 0) * H + c];
        float wk1 = Wk[(j + 1) * H + c];
        float wk2 = Wk[(j + 2) * H + c];
        float wk3 = Wk[(j + 3) * H + c];
#pragma unroll
        for (int r = 0; r < 16; ++r) {
            float4 hv = *(const float4*)(hsb + r * H + j);
            accq[r] += hv.x * wq0 + hv.y * wq1 + hv.z * wq2 + hv.w * wq3;
            acck[r] += hv.x * wk0 + hv.y * wk1 + hv.z * wk2 + hv.w * wk3;
        }
    }
#pragma unroll
    for (int r = 0; r < 16; ++r) {
        int row = row0 + rh * 16 + r;
        q[(size_t)row * H + c] = accq[r];
        k[(size_t)row * H + c] = acck[r];
    }
}

// ---------------- h_new = lrelu(agg@Wr + br) ----------------
__global__ __launch_bounds__(256) void k_gemm_r(const float* __restrict__ agg,
                                                const float* __restrict__ Wr,
                                                const float* __restrict__ br,
                                                float* __restrict__ hout) {
    __shared__ float hs[32 * H];
    int row0 = blockIdx.x * 32;
    int tid = threadIdx.x;

    const float4* src4 = (const float4*)(agg + (size_t)row0 * H);
    float4* dst4 = (float4*)hs;
#pragma unroll
    for (int i = 0; i < 4; ++i) dst4[tid + i * 256] = src4[tid + i * 256];
    __syncthreads();

    int c = tid & 127;
    int rh = tid >> 7;
    float acc[16];
    float bv = br[c];
#pragma unroll
    for (int r = 0; r < 16; ++r) acc[r] = bv;

    const float* hsb = hs + rh * 16 * H;
    for (int j4 = 0; j4 < 32; ++j4) {
        int j = j4 * 4;
        float w0 = Wr[(j + 0) * H + c];
        float w1 = Wr[(j + 1) * H + c];
        float w2 = Wr[(j + 2) * H + c];
        float w3 = Wr[(j + 3) * H + c];
#pragma unroll
        for (int r = 0; r < 16; ++r) {
            float4 hv = *(const float4*)(hsb + r * H + j);
            acc[r] += hv.x * w0 + hv.y * w1 + hv.z * w2 + hv.w * w3;
        }
    }
#pragma unroll
    for (int r = 0; r < 16; ++r) {
        int row = row0 + rh * 16 + r;
        hout[(size_t)row * H + c] = lrelu(acc[r]);
    }
}

// ---------------- graph sum pooling: hg[gid[n]] += h[n] ----------------
__global__ __launch_bounds__(256) void k_pool(const float* __restrict__ h,
                                              const int* __restrict__ gid,
                                              float* __restrict__ hg) {
    int gtid = blockIdx.x * blockDim.x + threadIdx.x;
    int wid = gtid >> 6;
    int lane = threadIdx.x & 63;
    int nw = (gridDim.x * blockDim.x) >> 6;
    for (int n = wid; n < NN; n += nw) {
        int g = gid[n];
        float2 hv = *(const float2*)(h + (size_t)n * H + lane * 2);
        float* ap = hg + (size_t)g * H + lane * 2;
        atomicAdd(ap, hv.x);
        atomicAdd(ap + 1, hv.y);
    }
}

// ---------------- MLP layer 1: x1 = hg@W1 + b1  [G,128]@[128,64] ----------------
__global__ void k_mlp1(const float* __restrict__ hg, const float* __restrict__ W1,
                       const float* __restrict__ b1, float* __restrict__ x1) {
    __shared__ float row[128];
    int g = blockIdx.x;
    int c = threadIdx.x;  // 64
    row[c] = hg[g * H + c];
    row[c + 64] = hg[g * H + c + 64];
    __syncthreads();
    float acc = b1[c];
    for (int j = 0; j < 128; ++j) acc += row[j] * W1[j * 64 + c];
    x1[g * 64 + c] = acc;
}

// ---------------- batchnorm stats over G rows ----------------
template <int C>
__global__ void k_bnstats(const float* __restrict__ x, float* __restrict__ stats) {
    int c = threadIdx.x;
    float sum = 0.f;
    for (int g = 0; g < NG; ++g) sum += x[g * C + c];
    float mu = sum / NG;
    float s2 = 0.f;
    for (int g = 0; g < NG; ++g) {
        float dv = x[g * C + c] - mu;
        s2 += dv * dv;
    }
    stats[c] = mu;
    stats[C + c] = rsqrtf(s2 / NG + 1e-5f);
}

// ---------------- batchnorm apply + lrelu (in place) ----------------
template <int C>
__global__ void k_bnapply(float* __restrict__ x, const float* __restrict__ stats,
                          const float* __restrict__ gm, const float* __restrict__ bt) {
    int i = blockIdx.x * blockDim.x + threadIdx.x;
    if (i >= NG * C) return;
    int c = i & (C - 1);
    float v = (x[i] - stats[c]) * stats[C + c] * gm[c] + bt[c];
    x[i] = lrelu(v);
}

// ---------------- MLP layer 2: x2 = x1@W2 + b2  [G,64]@[64,32] ----------------
__global__ void k_mlp2(const float* __restrict__ x1, const float* __restrict__ W2,
                       const float* __restrict__ b2, float* __restrict__ x2) {
    __shared__ float row[64];
    int g = blockIdx.x;
    int c = threadIdx.x;  // 32
    row[c] = x1[g * 64 + c];
    row[c + 32] = x1[g * 64 + c + 32];
    __syncthreads();
    float acc = b2[c];
    for (int j = 0; j < 64; ++j) acc += row[j] * W2[j * 32 + c];
    x2[g * 32 + c] = acc;
}

// ---------------- MLP layer 3: out = x2@W3 + b3  [G,32]@[32,1] ----------------
__global__ void k_mlp3(const float* __restrict__ x2, const float* __restrict__ W3,
                       const float* __restrict__ b3, float* __restrict__ out) {
    int g = blockIdx.x * blockDim.x + threadIdx.x;
    if (g >= NG) return;
    float acc = b3[0];
    for (int j = 0; j < 32; ++j) acc += x2[g * 32 + j] * W3[j];
    out[g] = acc;
}

extern "C" void kernel_launch(void* const* d_in, const int* in_sizes, int n_in,
                              void* d_out, int out_size, void* d_ws, size_t ws_size,
                              hipStream_t stream) {
    const int* nfeats = (const int*)d_in[0];
    // d_in[1] = efeats (unused by reference)
    const int* src = (const int*)d_in[2];
    const int* dst = (const int*)d_in[3];
    const int* gid = (const int*)d_in[4];
    const float* emb = (const float*)d_in[5];
    const float* Wq = (const float*)d_in[6];
    const float* bq = (const float*)d_in[7];
    const float* Wk = (const float*)d_in[8];
    const float* bk = (const float*)d_in[9];
    const float* Wr = (const float*)d_in[10];
    const float* br = (const float*)d_in[11];
    const float* W1 = (const float*)d_in[12];
    const float* b1 = (const float*)d_in[13];
    const float* g1 = (const float*)d_in[14];
    const float* be1 = (const float*)d_in[15];
    const float* W2 = (const float*)d_in[16];
    const float* b2 = (const float*)d_in[17];
    const float* g2 = (const float*)d_in[18];
    const float* be2 = (const float*)d_in[19];
    const float* W3 = (const float*)d_in[20];
    const float* b3 = (const float*)d_in[21];
    float* out = (float*)d_out;

    size_t nh = (size_t)NN * H;
    float* P0 = (float*)d_ws;
    float* P1 = P0 + nh;
    float* P2 = P1 + nh;
    float* hg = P2 + nh;
    float* x1 = hg + (size_t)NG * H;
    float* x2 = x1 + (size_t)NG * 64;
    float* st = x2 + (size_t)NG * 32;
    int* deg = (int*)(st + 2 * 64);  // doubles as scatter cursor
    int* rowp = deg + NN;            // NN+1
    int* csr_src = rowp + NN + 1;    // NE

    // ---- CSR build (dst-sorted adjacency) ----
    hipMemsetAsync(deg, 0, NN * sizeof(int), stream);
    k_hist<<<(NE + 255) / 256, 256, 0, stream>>>(dst, deg);
    k_scan<<<1, 1024, 0, stream>>>(deg, rowp);
    hipMemcpyAsync(deg, rowp, NN * sizeof(int), hipMemcpyDeviceToDevice, stream);
    k_scatter<<<(NE + 255) / 256, 256, 0, stream>>>(src, dst, deg, csr_src);

    k_atom<<<NN / 2, 256, 0, stream>>>(nfeats, emb, P0);

    float* h = P0;
    float* q = P1;
    float* k = P2;
    for (int l = 0; l < NLAYER; ++l) {
        k_gemm_qk<<<NN / 32, 256, 0, stream>>>(h, Wq + (size_t)l * H * H, bq + l * H,
                                               Wk + (size_t)l * H * H, bk + l * H, q, k);
        // h is dead after qk GEMM; reuse it as agg output (no memset needed)
        k_agg<<<(NN + 3) / 4, 256, 0, stream>>>(q, k, rowp, csr_src, h);
        k_gemm_r<<<NN / 32, 256, 0, stream>>>(h, Wr + (size_t)l * H * H, br + l * H, q);
        // rotate: new h lives in old q buffer
        float* newh = q;
        q = k;
        k = h;
        h = newh;
    }

    hipMemsetAsync(hg, 0, (size_t)NG * H * sizeof(float), stream);
    k_pool<<<2048, 256, 0, stream>>>(h, gid, hg);

    k_mlp1<<<NG, 64, 0, stream>>>(hg, W1, b1, x1);
    k_bnstats<64><<<1, 64, 0, stream>>>(x1, st);
    k_bnapply<64><<<(NG * 64 + 255) / 256, 256, 0, stream>>>(x1, st, g1, be1);
    k_mlp2<<<NG, 32, 0, stream>>>(x1, W2, b2, x2);
    k_bnstats<32><<<1, 32, 0, stream>>>(x2, st);
    k_bnapply<32><<<(NG * 32 + 255) / 256, 256, 0, stream>>>(x2, st, g2, be2);
    k_mlp3<<<(NG + 255) / 256, 256, 0, stream>>>(x2, W3, b3, out);
}

// Round 3
// 980.689 us; speedup vs baseline: 4.4424x; 1.6923x over previous
//
#include <hip/hip_runtime.h>

#define NN 100000
#define NP 100096   // padded rows (782 blocks * 128)
#define NE 1000000
#define NG 1000
#define H 128
#define NLAYER 4
#define NEG 0.2f
#define SCAN_BLOCKS 98

using short8 = __attribute__((ext_vector_type(8))) short;
using fx4 = __attribute__((ext_vector_type(4))) float;

__device__ __forceinline__ float lrelu(float x) { return x >= 0.f ? x : NEG * x; }

__device__ __forceinline__ unsigned short f2bf(float f) {
    union { float f; unsigned int u; } v;
    v.f = f;
    return (unsigned short)((v.u + 0x7fffu + ((v.u >> 16) & 1u)) >> 16);
}
__device__ __forceinline__ float bf2f(unsigned short h) {
    union { unsigned int u; float f; } v;
    v.u = ((unsigned int)h) << 16;
    return v.f;
}

// ---------------- Atom encoder: h[n][c] = sum_f emb[f][nfeats[n][f]][c]  (bf16 out) ----------------
__global__ __launch_bounds__(256) void k_atom(const int* __restrict__ nfeats,
                                              const float* __restrict__ emb,
                                              unsigned short* __restrict__ h) {
    int node = blockIdx.x * 4 + (threadIdx.x >> 6);
    if (node >= NN) return;
    int lane = threadIdx.x & 63;
    int c = lane * 2;
    float ax = 0.f, ay = 0.f;
#pragma unroll
    for (int f = 0; f < 9; ++f) {
        int idx = nfeats[node * 9 + f];
        float2 e = *(const float2*)(emb + (size_t)((f << 6) + idx) * H + c);
        ax += e.x;
        ay += e.y;
    }
    unsigned int packed = (unsigned int)f2bf(ax) | ((unsigned int)f2bf(ay) << 16);
    *(unsigned int*)(h + (size_t)node * H + c) = packed;
}

// ---------------- Weight prep: WT[mat][n][k] = bf16(W[mat][k][n]) ----------------
__global__ __launch_bounds__(256) void k_wt(const float* __restrict__ Wq,
                                            const float* __restrict__ Wk,
                                            const float* __restrict__ Wr,
                                            unsigned short* __restrict__ WT) {
    int mat = blockIdx.x;      // layer*3 + {0=q,1=k,2=r}
    int l = mat / 3;
    int kind = mat - l * 3;
    const float* src = (kind == 0 ? Wq : kind == 1 ? Wk : Wr) + (size_t)l * H * H;
    unsigned short* dst = WT + (size_t)mat * H * H;
    for (int idx = threadIdx.x; idx < H * H; idx += 256) {
        int kk = idx >> 7, n = idx & 127;
        dst[n * H + kk] = f2bf(src[idx]);
    }
}

// ---------------- CSR build ----------------
__global__ __launch_bounds__(256) void k_hist(const int* __restrict__ dst, int* __restrict__ deg) {
    int i = blockIdx.x * blockDim.x + threadIdx.x;
    if (i < NE) atomicAdd(&deg[dst[i]], 1);
}

__global__ __launch_bounds__(1024) void k_scan1(const int* __restrict__ deg,
                                                int* __restrict__ rowp,
                                                int* __restrict__ bsum) {
    __shared__ int tmp[1024];
    int t = threadIdx.x;
    int i = blockIdx.x * 1024 + t;
    int v = (i < NN) ? deg[i] : 0;
    tmp[t] = v;
    __syncthreads();
    for (int off = 1; off < 1024; off <<= 1) {
        int u = (t >= off) ? tmp[t - off] : 0;
        __syncthreads();
        tmp[t] += u;
        __syncthreads();
    }
    if (i < NN) rowp[i] = tmp[t] - v;  // block-local exclusive
    if (t == 1023) bsum[blockIdx.x] = tmp[1023];
}

__global__ __launch_bounds__(128) void k_scan2(int* __restrict__ bsum) {
    __shared__ int tmp[128];
    int t = threadIdx.x;
    int v = (t < SCAN_BLOCKS) ? bsum[t] : 0;
    tmp[t] = v;
    __syncthreads();
    for (int off = 1; off < 128; off <<= 1) {
        int u = (t >= off) ? tmp[t - off] : 0;
        __syncthreads();
        tmp[t] += u;
        __syncthreads();
    }
    if (t < SCAN_BLOCKS) bsum[t] = tmp[t] - v;  // exclusive block offsets
}

__global__ __launch_bounds__(256) void k_scan3(const int* __restrict__ bsum,
                                               int* __restrict__ rowp,
                                               int* __restrict__ cursor) {
    int i = blockIdx.x * blockDim.x + threadIdx.x;
    if (i < NN) {
        int v = rowp[i] + bsum[i >> 10];
        rowp[i] = v;
        cursor[i] = v;
    }
    if (i == 0) rowp[NN] = NE;
}

__global__ __launch_bounds__(256) void k_scatter(const int* __restrict__ src,
                                                 const int* __restrict__ dst,
                                                 int* __restrict__ cursor,
                                                 int* __restrict__ csr_src) {
    int i = blockIdx.x * blockDim.x + threadIdx.x;
    if (i < NE) {
        int pos = atomicAdd(&cursor[dst[i]], 1);
        csr_src[pos] = src[i];
    }
}

// ---------------- fused q/k GEMM via MFMA: q=h@Wq+bq, k=h@Wk+bk (bf16 in/out, fp32 acc) ----------------
__global__ __launch_bounds__(256) void k_qk_mfma(const unsigned short* __restrict__ h,
                                                 const unsigned short* __restrict__ WTq,
                                                 const float* __restrict__ bq,
                                                 const unsigned short* __restrict__ WTk,
                                                 const float* __restrict__ bk,
                                                 unsigned short* __restrict__ q,
                                                 unsigned short* __restrict__ k) {
    int lane = threadIdx.x & 63;
    int wave = threadIdx.x >> 6;
    int row0 = blockIdx.x * 128 + wave * 32;
    int lrow = lane & 15;
    int lk = (lane >> 4) << 3;

    short8 a[2][4];
#pragma unroll
    for (int rt = 0; rt < 2; ++rt)
#pragma unroll
        for (int ks = 0; ks < 4; ++ks)
            a[rt][ks] = *(const short8*)(h + (size_t)(row0 + rt * 16 + lrow) * H + ks * 32 + lk);

    fx4 aq[2][8], ak[2][8];
#pragma unroll
    for (int ct = 0; ct < 8; ++ct) {
        float vq = bq[ct * 16 + lrow];
        float vk = bk[ct * 16 + lrow];
#pragma unroll
        for (int rt = 0; rt < 2; ++rt) {
            aq[rt][ct] = fx4{vq, vq, vq, vq};
            ak[rt][ct] = fx4{vk, vk, vk, vk};
        }
    }

#pragma unroll
    for (int ks = 0; ks < 4; ++ks)
#pragma unroll
        for (int ct = 0; ct < 8; ++ct) {
            short8 wq = *(const short8*)(WTq + (ct * 16 + lrow) * H + ks * 32 + lk);
            short8 wk = *(const short8*)(WTk + (ct * 16 + lrow) * H + ks * 32 + lk);
#pragma unroll
            for (int rt = 0; rt < 2; ++rt) {
                aq[rt][ct] = __builtin_amdgcn_mfma_f32_16x16x32_bf16(a[rt][ks], wq, aq[rt][ct], 0, 0, 0);
                ak[rt][ct] = __builtin_amdgcn_mfma_f32_16x16x32_bf16(a[rt][ks], wk, ak[rt][ct], 0, 0, 0);
            }
        }

#pragma unroll
    for (int rt = 0; rt < 2; ++rt)
#pragma unroll
        for (int ct = 0; ct < 8; ++ct)
#pragma unroll
            for (int rg = 0; rg < 4; ++rg) {
                int r = row0 + rt * 16 + ((lane >> 4) << 2) + rg;
                if (r < NN) {
                    q[(size_t)r * H + ct * 16 + lrow] = f2bf(aq[rt][ct][rg]);
                    k[(size_t)r * H + ct * 16 + lrow] = f2bf(ak[rt][ct][rg]);
                }
            }
}

// ---------------- h_new = lrelu(agg@Wr + br) via MFMA ----------------
__global__ __launch_bounds__(256) void k_r_mfma(const unsigned short* __restrict__ agg,
                                                const unsigned short* __restrict__ WTr,
                                                const float* __restrict__ br,
                                                unsigned short* __restrict__ hout) {
    int lane = threadIdx.x & 63;
    int wave = threadIdx.x >> 6;
    int row0 = blockIdx.x * 128 + wave * 32;
    int lrow = lane & 15;
    int lk = (lane >> 4) << 3;

    short8 a[2][4];
#pragma unroll
    for (int rt = 0; rt < 2; ++rt)
#pragma unroll
        for (int ks = 0; ks < 4; ++ks)
            a[rt][ks] = *(const short8*)(agg + (size_t)(row0 + rt * 16 + lrow) * H + ks * 32 + lk);

    fx4 acc[2][8];
#pragma unroll
    for (int ct = 0; ct < 8; ++ct) {
        float v = br[ct * 16 + lrow];
#pragma unroll
        for (int rt = 0; rt < 2; ++rt) acc[rt][ct] = fx4{v, v, v, v};
    }

#pragma unroll
    for (int ks = 0; ks < 4; ++ks)
#pragma unroll
        for (int ct = 0; ct < 8; ++ct) {
            short8 w = *(const short8*)(WTr + (ct * 16 + lrow) * H + ks * 32 + lk);
#pragma unroll
            for (int rt = 0; rt < 2; ++rt)
                acc[rt][ct] = __builtin_amdgcn_mfma_f32_16x16x32_bf16(a[rt][ks], w, acc[rt][ct], 0, 0, 0);
        }

#pragma unroll
    for (int rt = 0; rt < 2; ++rt)
#pragma unroll
        for (int ct = 0; ct < 8; ++ct)
#pragma unroll
            for (int rg = 0; rg < 4; ++rg) {
                int r = row0 + rt * 16 + ((lane >> 4) << 2) + rg;
                if (r < NN)
                    hout[(size_t)r * H + ct * 16 + lrow] = f2bf(lrelu(acc[rt][ct][rg]));
            }
}

// ---------------- aggregation (gather): agg[n] = sum_e lrelu(q[n]+k[src_e])  (bf16) ----------------
__global__ __launch_bounds__(256) void k_agg(const unsigned short* __restrict__ q,
                                             const unsigned short* __restrict__ kk,
                                             const int* __restrict__ rowp,
                                             const int* __restrict__ csr_src,
                                             unsigned short* __restrict__ agg) {
    int node = blockIdx.x * 4 + (threadIdx.x >> 6);
    if (node >= NN) return;
    int lane = threadIdx.x & 63;
    int start = rowp[node];
    int end = rowp[node + 1];
    unsigned int qp = *(const unsigned int*)(q + (size_t)node * H + lane * 2);
    float qx = bf2f((unsigned short)(qp & 0xffff));
    float qy = bf2f((unsigned short)(qp >> 16));
    float ax = 0.f, ay = 0.f;
    for (int base = start; base < end; base += 64) {
        int cnt = end - base;
        if (cnt > 64) cnt = 64;
        int sid = (lane < cnt) ? csr_src[base + lane] : 0;
        for (int j = 0; j < cnt; ++j) {
            int s = __shfl(sid, j);
            unsigned int kp = *(const unsigned int*)(kk + (size_t)s * H + lane * 2);
            ax += lrelu(qx + bf2f((unsigned short)(kp & 0xffff)));
            ay += lrelu(qy + bf2f((unsigned short)(kp >> 16)));
        }
    }
    unsigned int o = (unsigned int)f2bf(ax) | ((unsigned int)f2bf(ay) << 16);
    *(unsigned int*)(agg + (size_t)node * H + lane * 2) = o;
}

// ---------------- graph sum pooling (bf16 in, fp32 out) ----------------
__global__ __launch_bounds__(256) void k_pool(const unsigned short* __restrict__ h,
                                              const int* __restrict__ gid,
                                              float* __restrict__ hg) {
    int gtid = blockIdx.x * blockDim.x + threadIdx.x;
    int wid = gtid >> 6;
    int lane = threadIdx.x & 63;
    int nw = (gridDim.x * blockDim.x) >> 6;
    for (int n = wid; n < NN; n += nw) {
        int g = gid[n];
        unsigned int hp = *(const unsigned int*)(h + (size_t)n * H + lane * 2);
        float* ap = hg + (size_t)g * H + lane * 2;
        atomicAdd(ap, bf2f((unsigned short)(hp & 0xffff)));
        atomicAdd(ap + 1, bf2f((unsigned short)(hp >> 16)));
    }
}

// ---------------- MLP head (fp32, tiny) ----------------
__global__ void k_mlp1(const float* __restrict__ hg, const float* __restrict__ W1,
                       const float* __restrict__ b1, float* __restrict__ x1) {
    __shared__ float row[128];
    int g = blockIdx.x;
    int c = threadIdx.x;  // 64
    row[c] = hg[g * H + c];
    row[c + 64] = hg[g * H + c + 64];
    __syncthreads();
    float acc = b1[c];
    for (int j = 0; j < 128; ++j) acc += row[j] * W1[j * 64 + c];
    x1[g * 64 + c] = acc;
}

template <int C>
__global__ void k_bnstats(const float* __restrict__ x, float* __restrict__ stats) {
    int c = threadIdx.x;
    float sum = 0.f;
    for (int g = 0; g < NG; ++g) sum += x[g * C + c];
    float mu = sum / NG;
    float s2 = 0.f;
    for (int g = 0; g < NG; ++g) {
        float dv = x[g * C + c] - mu;
        s2 += dv * dv;
    }
    stats[c] = mu;
    stats[C + c] = rsqrtf(s2 / NG + 1e-5f);
}

template <int C>
__global__ void k_bnapply(float* __restrict__ x, const float* __restrict__ stats,
                          const float* __restrict__ gm, const float* __restrict__ bt) {
    int i = blockIdx.x * blockDim.x + threadIdx.x;
    if (i >= NG * C) return;
    int c = i & (C - 1);
    float v = (x[i] - stats[c]) * stats[C + c] * gm[c] + bt[c];
    x[i] = lrelu(v);
}

__global__ void k_mlp2(const float* __restrict__ x1, const float* __restrict__ W2,
                       const float* __restrict__ b2, float* __restrict__ x2) {
    __shared__ float row[64];
    int g = blockIdx.x;
    int c = threadIdx.x;  // 32
    row[c] = x1[g * 64 + c];
    row[c + 32] = x1[g * 64 + c + 32];
    __syncthreads();
    float acc = b2[c];
    for (int j = 0; j < 64; ++j) acc += row[j] * W2[j * 32 + c];
    x2[g * 32 + c] = acc;
}

__global__ void k_mlp3(const float* __restrict__ x2, const float* __restrict__ W3,
                       const float* __restrict__ b3, float* __restrict__ out) {
    int g = blockIdx.x * blockDim.x + threadIdx.x;
    if (g >= NG) return;
    float acc = b3[0];
    for (int j = 0; j < 32; ++j) acc += x2[g * 32 + j] * W3[j];
    out[g] = acc;
}

extern "C" void kernel_launch(void* const* d_in, const int* in_sizes, int n_in,
                              void* d_out, int out_size, void* d_ws, size_t ws_size,
                              hipStream_t stream) {
    const int* nfeats = (const int*)d_in[0];
    // d_in[1] = efeats (unused by reference)
    const int* src = (const int*)d_in[2];
    const int* dst = (const int*)d_in[3];
    const int* gid = (const int*)d_in[4];
    const float* emb = (const float*)d_in[5];
    const float* Wq = (const float*)d_in[6];
    const float* bq = (const float*)d_in[7];
    const float* Wk = (const float*)d_in[8];
    const float* bk = (const float*)d_in[9];
    const float* Wr = (const float*)d_in[10];
    const float* br = (const float*)d_in[11];
    const float* W1 = (const float*)d_in[12];
    const float* b1 = (const float*)d_in[13];
    const float* g1 = (const float*)d_in[14];
    const float* be1 = (const float*)d_in[15];
    const float* W2 = (const float*)d_in[16];
    const float* b2 = (const float*)d_in[17];
    const float* g2 = (const float*)d_in[18];
    const float* be2 = (const float*)d_in[19];
    const float* W3 = (const float*)d_in[20];
    const float* b3 = (const float*)d_in[21];
    float* out = (float*)d_out;

    size_t nh = (size_t)NP * H;  // bf16 elements per node buffer
    unsigned short* P0 = (unsigned short*)d_ws;
    unsigned short* P1 = P0 + nh;
    unsigned short* P2 = P1 + nh;
    unsigned short* WT = P2 + nh;                // 12 * 128*128 bf16
    float* hg = (float*)(WT + 12 * H * H);
    float* x1 = hg + (size_t)NG * H;
    float* x2 = x1 + (size_t)NG * 64;
    float* st = x2 + (size_t)NG * 32;
    int* cursor = (int*)(st + 2 * 64);  // NN (also used as deg for histogram)
    int* rowp = cursor + NN;            // NN+1
    int* bsum = rowp + NN + 1;          // 128
    int* csr_src = bsum + 128;          // NE

    // ---- CSR build (dst-sorted adjacency) ----
    hipMemsetAsync(cursor, 0, NN * sizeof(int), stream);
    k_hist<<<(NE + 255) / 256, 256, 0, stream>>>(dst, cursor);
    k_scan1<<<SCAN_BLOCKS, 1024, 0, stream>>>(cursor, rowp, bsum);
    k_scan2<<<1, 128, 0, stream>>>(bsum);
    k_scan3<<<(NN + 255) / 256, 256, 0, stream>>>(bsum, rowp, cursor);
    k_scatter<<<(NE + 255) / 256, 256, 0, stream>>>(src, dst, cursor, csr_src);

    // ---- weight prep + atom encoder ----
    k_wt<<<12, 256, 0, stream>>>(Wq, Wk, Wr, WT);
    k_atom<<<NN / 4, 256, 0, stream>>>(nfeats, emb, P0);

    unsigned short* h = P0;
    unsigned short* q = P1;
    unsigned short* k = P2;
    const int NB = NP / 128;  // 782
    for (int l = 0; l < NLAYER; ++l) {
        k_qk_mfma<<<NB, 256, 0, stream>>>(h, WT + (size_t)(l * 3 + 0) * H * H, bq + l * H,
                                          WT + (size_t)(l * 3 + 1) * H * H, bk + l * H, q, k);
        // h is dead after qk GEMM; reuse it as agg output
        k_agg<<<(NN + 3) / 4, 256, 0, stream>>>(q, k, rowp, csr_src, h);
        k_r_mfma<<<NB, 256, 0, stream>>>(h, WT + (size_t)(l * 3 + 2) * H * H, br + l * H, q);
        unsigned short* newh = q;
        q = k;
        k = h;
        h = newh;
    }

    hipMemsetAsync(hg, 0, (size_t)NG * H * sizeof(float), stream);
    k_pool<<<2048, 256, 0, stream>>>(h, gid, hg);

    k_mlp1<<<NG, 64, 0, stream>>>(hg, W1, b1, x1);
    k_bnstats<64><<<1, 64, 0, stream>>>(x1, st);
    k_bnapply<64><<<(NG * 64 + 255) / 256, 256, 0, stream>>>(x1, st, g1, be1);
    k_mlp2<<<NG, 32, 0, stream>>>(x1, W2, b2, x2);
    k_bnstats<32><<<1, 32, 0, stream>>>(x2, st);
    k_bnapply<32><<<(NG * 32 + 255) / 256, 256, 0, stream>>>(x2, st, g2, be2);
    k_mlp3<<<(NG + 255) / 256, 256, 0, stream>>>(x2, W3, b3, out);
}